// Round 3
// baseline (431.478 us; speedup 1.0000x reference)
//
#include <hip/hip_runtime.h>
#include <math.h>

// MoE router: logits = x @ gate_w  (M=32768, K=2048, N=64 fp32)
// outputs (concat flat, read back as float32):
//   [0 .. 2N)   top_k_weights [N,2]
//   [2N .. 4N)  top_k_indices [N,2] (as float values)
//   [4N]        load_balance_loss scalar
#define N_TOKENS 32768
#define HIDDEN   2048
#define NEXP     64
#define BM 64                  // tokens per block
#define NBLK (N_TOKENS / BM)   // 512 blocks
#define NWAVE 8                // 512 threads

__global__ __launch_bounds__(512, 4)
void router_main(const float* __restrict__ x, const float* __restrict__ gw,
                 float* __restrict__ out_w, float* __restrict__ out_i,
                 float* __restrict__ wsP, int* __restrict__ wsC)
{
    __shared__ float logits_s[BM][NEXP];   // 16 KB
    __shared__ float pred[NWAVE][NEXP];
    __shared__ int   cntl[NEXP];

    const int tid = threadIdx.x;           // 0..511
    const int eg  = tid & 15;              // expert group: experts eg*4 .. eg*4+3
    const int tg  = tid >> 4;              // token group:  tokens  tg*2 .. tg*2+1
    const int m0  = blockIdx.x * BM;
    if (tid < NEXP) cntl[tid] = 0;

    // x rows for this thread's two tokens (16-lane groups share addresses -> L1 broadcast)
    const float4* x0 = reinterpret_cast<const float4*>(x + (size_t)(m0 + tg * 2) * HIDDEN);
    const float4* x1 = x0 + (HIDDEN / 4);
    // gate_w column quad for this thread's experts; every wave reads the same lines (L1-hot)
    const float4* wq = reinterpret_cast<const float4*>(gw) + eg;

    float acc[2][4];
    #pragma unroll
    for (int j = 0; j < 2; ++j)
        #pragma unroll
        for (int e = 0; e < 4; ++e) acc[j][e] = 0.f;

    #pragma unroll 2
    for (int kq = 0; kq < HIDDEN / 4; ++kq) {
        const float4 a0 = x0[kq];
        const float4 a1 = x1[kq];
        const float4 w0 = wq[(kq * 4 + 0) * 16];
        const float4 w1 = wq[(kq * 4 + 1) * 16];
        const float4 w2 = wq[(kq * 4 + 2) * 16];
        const float4 w3 = wq[(kq * 4 + 3) * 16];
        const float a0c[4] = {a0.x, a0.y, a0.z, a0.w};
        const float a1c[4] = {a1.x, a1.y, a1.z, a1.w};
        const float4 wc[4] = {w0, w1, w2, w3};
        #pragma unroll
        for (int c = 0; c < 4; ++c) {
            acc[0][0] = fmaf(a0c[c], wc[c].x, acc[0][0]);
            acc[0][1] = fmaf(a0c[c], wc[c].y, acc[0][1]);
            acc[0][2] = fmaf(a0c[c], wc[c].z, acc[0][2]);
            acc[0][3] = fmaf(a0c[c], wc[c].w, acc[0][3]);
            acc[1][0] = fmaf(a1c[c], wc[c].x, acc[1][0]);
            acc[1][1] = fmaf(a1c[c], wc[c].y, acc[1][1]);
            acc[1][2] = fmaf(a1c[c], wc[c].z, acc[1][2]);
            acc[1][3] = fmaf(a1c[c], wc[c].w, acc[1][3]);
        }
    }

    // dump logits to LDS (once): rows tg*2+j, cols eg*4..+3 — contiguous float4 per 16 lanes
    #pragma unroll
    for (int j = 0; j < 2; ++j)
        *reinterpret_cast<float4*>(&logits_s[tg * 2 + j][eg * 4]) =
            make_float4(acc[j][0], acc[j][1], acc[j][2], acc[j][3]);
    __syncthreads();

    // epilogue: wave wv handles tokens wv*8 .. wv*8+7; lane = expert
    const int wv   = tid >> 6;
    const int lane = tid & 63;
    const int TPW  = BM / NWAVE;   // 8
    float sumP = 0.f;              // per-lane: sum over tokens of prob for expert==lane
    for (int t = 0; t < TPW; ++t) {
        const int m = wv * TPW + t;
        const float l = logits_s[m][lane];
        // top-1 (max value, lowest index on tie — matches jax.lax.top_k)
        float v = l; int idx = lane;
        #pragma unroll
        for (int off = 32; off >= 1; off >>= 1) {
            float ov = __shfl_xor(v, off);
            int   oi = __shfl_xor(idx, off);
            if (ov > v || (ov == v && oi < idx)) { v = ov; idx = oi; }
        }
        const float v1 = v; const int i1 = idx;
        // top-2
        v = (lane == i1) ? -INFINITY : l;
        idx = lane;
        #pragma unroll
        for (int off = 32; off >= 1; off >>= 1) {
            float ov = __shfl_xor(v, off);
            int   oi = __shfl_xor(idx, off);
            if (ov > v || (ov == v && oi < idx)) { v = ov; idx = oi; }
        }
        const float v2 = v; const int i2 = idx;
        // softmax over the two top logits (stable: v2 - v1 <= 0)
        const float ed  = expf(v2 - v1);
        const float wt1 = 1.f / (1.f + ed);
        const float wt2 = ed / (1.f + ed);
        // full softmax over 64 experts (max is v1)
        const float p = expf(l - v1);
        float Z = p;
        #pragma unroll
        for (int off = 32; off >= 1; off >>= 1) Z += __shfl_xor(Z, off);
        sumP += p / Z;
        if (lane == 0) {
            const size_t o = (size_t)(m0 + m) * 2;
            out_w[o]     = wt1;
            out_w[o + 1] = wt2;
            out_i[o]     = (float)i1;
            out_i[o + 1] = (float)i2;
            atomicAdd(&cntl[i1], 1);
            atomicAdd(&cntl[i2], 1);
        }
    }
    pred[wv][lane] = sumP;
    __syncthreads();
    if (tid < NEXP) {
        float s = 0.f;
        #pragma unroll
        for (int w2 = 0; w2 < NWAVE; ++w2) s += pred[w2][tid];
        wsP[(size_t)blockIdx.x * NEXP + tid] = s;
        wsC[(size_t)blockIdx.x * NEXP + tid] = cntl[tid];
    }
}

__global__ void router_finalize(const float* __restrict__ wsP, const int* __restrict__ wsC,
                                float* __restrict__ out_loss)
{
    const int e = threadIdx.x;   // 64 threads, lane = expert
    float P = 0.f, C = 0.f;
    for (int b = 0; b < NBLK; ++b) {
        P += wsP[(size_t)b * NEXP + e];
        C += (float)wsC[(size_t)b * NEXP + e];
    }
    float val = (C / (float)N_TOKENS) * (P / (float)N_TOKENS);
    #pragma unroll
    for (int off = 32; off >= 1; off >>= 1) val += __shfl_xor(val, off);
    if (e == 0) out_loss[0] = (float)NEXP * val;
}

extern "C" void kernel_launch(void* const* d_in, const int* in_sizes, int n_in,
                              void* d_out, int out_size, void* d_ws, size_t ws_size,
                              hipStream_t stream) {
    const float* x  = (const float*)d_in[0];
    const float* gw = (const float*)d_in[1];
    float* out   = (float*)d_out;
    float* out_w = out;                        // [N,2] weights
    float* out_i = out + (size_t)N_TOKENS * 2; // [N,2] indices (as floats)
    float* loss  = out + (size_t)N_TOKENS * 4; // scalar
    float* wsP = (float*)d_ws;                                  // [NBLK][64]
    int*   wsC = (int*)((char*)d_ws + (size_t)NBLK * NEXP * 4); // [NBLK][64]
    hipLaunchKernelGGL(router_main, dim3(NBLK), dim3(512), 0, stream,
                       x, gw, out_w, out_i, wsP, wsC);
    hipLaunchKernelGGL(router_finalize, dim3(1), dim3(64), 0, stream, wsP, wsC, loss);
}

// Round 4
// 230.354 us; speedup vs baseline: 1.8731x; 1.8731x over previous
//
#include <hip/hip_runtime.h>
#include <math.h>

// MoE router: logits = x @ gate_w  (M=32768, K=2048, N=64 fp32)
// outputs (concat flat, read back as float32):
//   [0 .. 2N)   top_k_weights [N,2]
//   [2N .. 4N)  top_k_indices [N,2] (as float values)
//   [4N]        load_balance_loss scalar
#define N_TOKENS 32768
#define HIDDEN   2048
#define NEXP     64
#define BM 64                  // tokens per block (1 per lane)
#define BK 64                  // k chunk
#define NCHUNK (HIDDEN / BK)   // 32
#define EPW 16                 // experts per wave
#define NWAVE 4                // 256 threads
#define NBLK (N_TOKENS / BM)   // 512 blocks

__global__ __launch_bounds__(256, 2)
void router_main(const float* __restrict__ x, const float* __restrict__ gw,
                 float* __restrict__ out_w, float* __restrict__ out_i,
                 float* __restrict__ wsP, int* __restrict__ wsC)
{
    __shared__ float xs[2][BK][BM + 1];      // column-major x tile, 2-way banks everywhere
    __shared__ float logits_s[BM][NEXP + 1]; // padded for lane=expert reads
    __shared__ float pred[NWAVE][NEXP];
    __shared__ int   cntl[NEXP];

    const int tid  = threadIdx.x;
    const int lane = tid & 63;                                 // token within block
    const int wv   = tid >> 6;                                 // wave id
    const int e0   = __builtin_amdgcn_readfirstlane(wv * EPW); // expert base (SGPR)
    const int m0   = blockIdx.x * BM;
    if (tid < NEXP) cntl[tid] = 0;

    // staging decomposition: idx = tid + 256*r -> (token, float4-slot)
    const int f4   = tid & 15;
    const int tokb = tid >> 4;   // + 16*r

    float acc[EPW];
    #pragma unroll
    for (int j = 0; j < EPW; ++j) acc[j] = 0.f;

    float4 pf[4];
    // ---- prologue: load + write chunk 0 ----
    #pragma unroll
    for (int r = 0; r < 4; ++r)
        pf[r] = *reinterpret_cast<const float4*>(
            x + (size_t)(m0 + tokb + 16 * r) * HIDDEN + f4 * 4);
    #pragma unroll
    for (int r = 0; r < 4; ++r) {
        const int tok = tokb + 16 * r;
        xs[0][f4 * 4 + 0][tok] = pf[r].x;
        xs[0][f4 * 4 + 1][tok] = pf[r].y;
        xs[0][f4 * 4 + 2][tok] = pf[r].z;
        xs[0][f4 * 4 + 3][tok] = pf[r].w;
    }
    __syncthreads();

    int buf = 0;
    for (int c = 0; c < NCHUNK; ++c) {
        // issue next chunk's global loads early (latency hides under compute)
        if (c + 1 < NCHUNK) {
            #pragma unroll
            for (int r = 0; r < 4; ++r)
                pf[r] = *reinterpret_cast<const float4*>(
                    x + (size_t)(m0 + tokb + 16 * r) * HIDDEN + (c + 1) * BK + f4 * 4);
        }
        // compute: w via wave-uniform scalar loads, x via conflict-free LDS b32
        const float* wrow = gw + (size_t)c * BK * NEXP + e0;
        #pragma unroll 4
        for (int k = 0; k < BK; ++k) {
            const float xv = xs[buf][k][lane];
            const float* wr = wrow + (size_t)k * NEXP;
            #pragma unroll
            for (int j = 0; j < EPW; ++j)
                acc[j] = fmaf(xv, wr[j], acc[j]);
        }
        if (c + 1 < NCHUNK) {
            #pragma unroll
            for (int r = 0; r < 4; ++r) {
                const int tok = tokb + 16 * r;
                xs[buf ^ 1][f4 * 4 + 0][tok] = pf[r].x;
                xs[buf ^ 1][f4 * 4 + 1][tok] = pf[r].y;
                xs[buf ^ 1][f4 * 4 + 2][tok] = pf[r].z;
                xs[buf ^ 1][f4 * 4 + 3][tok] = pf[r].w;
            }
        }
        __syncthreads();
        buf ^= 1;
    }

    // dump logits: wave wv owns experts e0..e0+15 for all 64 tokens
    #pragma unroll
    for (int j = 0; j < EPW; ++j)
        logits_s[lane][e0 + j] = acc[j];
    __syncthreads();

    // epilogue: wave wv handles tokens wv*16..+15; lane = expert
    const int TPW = BM / NWAVE;   // 16
    float sumP = 0.f;             // per-lane: sum over tokens of prob for expert==lane
    for (int t = 0; t < TPW; ++t) {
        const int m = wv * TPW + t;
        const float l = logits_s[m][lane];
        // top-1 (max value, lowest index on tie — matches jax.lax.top_k)
        float v = l; int idx = lane;
        #pragma unroll
        for (int off = 32; off >= 1; off >>= 1) {
            float ov = __shfl_xor(v, off);
            int   oi = __shfl_xor(idx, off);
            if (ov > v || (ov == v && oi < idx)) { v = ov; idx = oi; }
        }
        const float v1 = v; const int i1 = idx;
        // top-2
        v = (lane == i1) ? -INFINITY : l;
        idx = lane;
        #pragma unroll
        for (int off = 32; off >= 1; off >>= 1) {
            float ov = __shfl_xor(v, off);
            int   oi = __shfl_xor(idx, off);
            if (ov > v || (ov == v && oi < idx)) { v = ov; idx = oi; }
        }
        const float v2 = v; const int i2 = idx;
        // softmax over the two top logits (stable: v2 - v1 <= 0)
        const float ed  = expf(v2 - v1);
        const float wt1 = 1.f / (1.f + ed);
        const float wt2 = ed / (1.f + ed);
        // full softmax over 64 experts (max is v1)
        const float p = expf(l - v1);
        float Z = p;
        #pragma unroll
        for (int off = 32; off >= 1; off >>= 1) Z += __shfl_xor(Z, off);
        sumP += p / Z;
        if (lane == 0) {
            const size_t o = (size_t)(m0 + m) * 2;
            out_w[o]     = wt1;
            out_w[o + 1] = wt2;
            out_i[o]     = (float)i1;
            out_i[o + 1] = (float)i2;
            atomicAdd(&cntl[i1], 1);
            atomicAdd(&cntl[i2], 1);
        }
    }
    pred[wv][lane] = sumP;
    __syncthreads();
    if (tid < NEXP) {
        float s = 0.f;
        #pragma unroll
        for (int w2 = 0; w2 < NWAVE; ++w2) s += pred[w2][tid];
        wsP[(size_t)blockIdx.x * NEXP + tid] = s;
        wsC[(size_t)blockIdx.x * NEXP + tid] = cntl[tid];
    }
}

__global__ void router_finalize(const float* __restrict__ wsP, const int* __restrict__ wsC,
                                float* __restrict__ out_loss)
{
    const int e = threadIdx.x;   // 64 threads, lane = expert
    float P = 0.f, C = 0.f;
    for (int b = 0; b < NBLK; ++b) {
        P += wsP[(size_t)b * NEXP + e];
        C += (float)wsC[(size_t)b * NEXP + e];
    }
    float val = (C / (float)N_TOKENS) * (P / (float)N_TOKENS);
    #pragma unroll
    for (int off = 32; off >= 1; off >>= 1) val += __shfl_xor(val, off);
    if (e == 0) out_loss[0] = (float)NEXP * val;
}

extern "C" void kernel_launch(void* const* d_in, const int* in_sizes, int n_in,
                              void* d_out, int out_size, void* d_ws, size_t ws_size,
                              hipStream_t stream) {
    const float* x  = (const float*)d_in[0];
    const float* gw = (const float*)d_in[1];
    float* out   = (float*)d_out;
    float* out_w = out;                        // [N,2] weights
    float* out_i = out + (size_t)N_TOKENS * 2; // [N,2] indices (as floats)
    float* loss  = out + (size_t)N_TOKENS * 4; // scalar
    float* wsP = (float*)d_ws;                                  // [NBLK][64]
    int*   wsC = (int*)((char*)d_ws + (size_t)NBLK * NEXP * 4); // [NBLK][64]
    hipLaunchKernelGGL(router_main, dim3(NBLK), dim3(256), 0, stream,
                       x, gw, out_w, out_i, wsP, wsC);
    hipLaunchKernelGGL(router_finalize, dim3(1), dim3(64), 0, stream, wsP, wsC, loss);
}